// Round 16
// baseline (173.621 us; speedup 1.0000x reference)
//
#include <hip/hip_runtime.h>
#include <hip/hip_bf16.h>
#include <hip/hip_fp16.h>
#include <cstdint>
#include <cstddef>

#define BB 32
#define NN 256
#define MM 256
#define DD 512
#define NEGF (-1e9f)
#define LOG2E 1.4426950408889634f
#define SPLN 82176   // 321*256 floats: th/a skew planes per batch
#define QPLN 82176   // 321*64 u32x4 in 4B words per batch

typedef __fp16 h2 __attribute__((ext_vector_type(2)));
typedef float f32x4_t __attribute__((ext_vector_type(4)));
typedef unsigned int u32x4_t __attribute__((ext_vector_type(4)));
typedef short s16x8 __attribute__((ext_vector_type(8)));

__device__ __forceinline__ uint32_t pack_q(float a, float b) {
  h2 r = __builtin_amdgcn_cvt_pkrtz(a, b);
  return __builtin_bit_cast(uint32_t, r);
}
__device__ __forceinline__ float2 unpack_q(uint32_t u) {
  h2 r = __builtin_bit_cast(h2, u);
  return make_float2((float)r.x, (float)r.y);
}
__device__ __forceinline__ float softplus_f(float x) {
  return fmaxf(x, 0.f) + __logf(1.f + __expf(-fabsf(x)));
}
__device__ __forceinline__ float logsig_f(float x) {
  return fminf(x, 0.f) - __logf(1.f + __expf(-fabsf(x)));
}
__device__ __forceinline__ short f2bf(float f) {   // RNE f32 -> bf16 bits
  uint32_t u = __builtin_bit_cast(uint32_t, f);
  u += 0x7FFFu + ((u >> 16) & 1u);
  return (short)(u >> 16);
}

#define WAITV(N) do { \
  asm volatile("s_waitcnt vmcnt(" #N ")" ::: "memory"); \
  __builtin_amdgcn_sched_barrier(0); \
} while (0)

#define DRAIN() do { \
  asm volatile("s_waitcnt vmcnt(0) lgkmcnt(0)" ::: "memory"); \
  __builtin_amdgcn_sched_barrier(0); \
} while (0)

#define SBAR() __builtin_amdgcn_sched_barrier(0)

// ---------- bf16-MFMA GEMM + activation + skew side store (both ops) -------
__global__ __launch_bounds__(256) void gemm_mfma(const float* __restrict__ ZX,
                                                 const float* __restrict__ ZY,
                                                 const float* __restrict__ GX,
                                                 const float* __restrict__ GY,
                                                 float* __restrict__ theta,
                                                 float* __restrict__ Amat,
                                                 float* __restrict__ thS,
                                                 float* __restrict__ aS) {
  const int z  = blockIdx.z;
  const int b  = z & 31;
  const int op = z >> 5;
  const int ty = blockIdx.y;
  const int tx = blockIdx.x;
  const float* Xb = (op ? GX : ZX) + (size_t)b * NN * DD;
  const float* Yb = (op ? GY : ZY) + (size_t)b * MM * DD;
  float* outb = (op ? Amat : theta) + (size_t)b * NN * MM;
  float* skb  = (op ? aS : thS) + (size_t)b * SPLN;

  __shared__ short xs[64][40];
  __shared__ short ys[64][40];

  const int tid = threadIdx.x;
  const int l   = tid & 63;
  const int w   = tid >> 6;
  const int r0  = (w >> 1) * 32;
  const int c0  = (w & 1) * 32;
  const int srow = tid >> 2;
  const int scg  = (tid & 3) * 8;

  f32x4_t acc[2][2];
  #pragma unroll
  for (int i = 0; i < 2; ++i)
    #pragma unroll
    for (int j = 0; j < 2; ++j) acc[i][j] = f32x4_t{0.f, 0.f, 0.f, 0.f};

  const int lr = l & 15;
  const int kof = (l >> 4) * 8;

  for (int ks = 0; ks < 16; ++ks) {
    const int k0 = ks * 32;
    const float4 xv0 = *(const float4*)(Xb + (size_t)(ty * 64 + srow) * DD + k0 + scg);
    const float4 xv1 = *(const float4*)(Xb + (size_t)(ty * 64 + srow) * DD + k0 + scg + 4);
    const float4 yv0 = *(const float4*)(Yb + (size_t)(tx * 64 + srow) * DD + k0 + scg);
    const float4 yv1 = *(const float4*)(Yb + (size_t)(tx * 64 + srow) * DD + k0 + scg + 4);
    __syncthreads();
    s16x8 xp, yp;
    xp[0] = f2bf(xv0.x); xp[1] = f2bf(xv0.y); xp[2] = f2bf(xv0.z); xp[3] = f2bf(xv0.w);
    xp[4] = f2bf(xv1.x); xp[5] = f2bf(xv1.y); xp[6] = f2bf(xv1.z); xp[7] = f2bf(xv1.w);
    yp[0] = f2bf(yv0.x); yp[1] = f2bf(yv0.y); yp[2] = f2bf(yv0.z); yp[3] = f2bf(yv0.w);
    yp[4] = f2bf(yv1.x); yp[5] = f2bf(yv1.y); yp[6] = f2bf(yv1.z); yp[7] = f2bf(yv1.w);
    *(s16x8*)&xs[srow][scg] = xp;
    *(s16x8*)&ys[srow][scg] = yp;
    __syncthreads();
    const s16x8 a0 = *(const s16x8*)&xs[r0 + lr][kof];
    const s16x8 a1 = *(const s16x8*)&xs[r0 + 16 + lr][kof];
    const s16x8 b0 = *(const s16x8*)&ys[c0 + lr][kof];
    const s16x8 b1 = *(const s16x8*)&ys[c0 + 16 + lr][kof];
    acc[0][0] = __builtin_amdgcn_mfma_f32_16x16x32_bf16(a0, b0, acc[0][0], 0, 0, 0);
    acc[0][1] = __builtin_amdgcn_mfma_f32_16x16x32_bf16(a0, b1, acc[0][1], 0, 0, 0);
    acc[1][0] = __builtin_amdgcn_mfma_f32_16x16x32_bf16(a1, b0, acc[1][0], 0, 0, 0);
    acc[1][1] = __builtin_amdgcn_mfma_f32_16x16x32_bf16(a1, b1, acc[1][1], 0, 0, 0);
  }

  #pragma unroll
  for (int i = 0; i < 2; ++i) {
    #pragma unroll
    for (int j = 0; j < 2; ++j) {
      #pragma unroll
      for (int r = 0; r < 4; ++r) {
        const int R = ty * 64 + r0 + i * 16 + (l >> 4) * 4 + r;
        const int C = tx * 64 + c0 + j * 16 + (l & 15);
        const float v = acc[i][j][r];
        const float act = (op == 0) ? softplus_f(v) : logsig_f(v);
        outb[(size_t)R * MM + C] = act;
        skb[(size_t)(C + 1 + (R >> 2)) * 256 + R] = act * LOG2E;
      }
    }
  }
}

// -------- wave-synchronous soft-NW, skewed, 8-plane fwd segments ----------
// One wave per batch; lane t owns grid rows 4t+1..4t+4, col j = m - t.
// Fwd: 3 banks x 8 planes (th+a), WAITV 32/40/48. Bwd: 3 banks x 4 planes,
// direct ALN scatter stores (untwist fused), WAITV 8/24/40. Stores always
// issue (cndmask'd dump address for inactive lanes) so vmcnt is exact.
__global__ __launch_bounds__(64, 1) void nw_wave(const float* __restrict__ thSA,
                                                 const float* __restrict__ aSA,
                                                 u32x4_t* __restrict__ qSA,
                                                 float* __restrict__ aln,
                                                 float* __restrict__ dmpA) {
  const int b = blockIdx.x;
  const int t = threadIdx.x;
  const float* thS = thSA + (size_t)b * SPLN;
  const float* aS  = aSA  + (size_t)b * SPLN;
  u32x4_t* qS = qSA + (size_t)b * (QPLN / 4);
  float* ALN = aln + (size_t)b * NN * MM;
  float* dmp = dmpA + (size_t)b * 64 + t;

  __shared__ f32x4_t stg[48][64];  // fwd: 3 banks x 16 rows (8 th + 8 a)

  // ================= forward =================
  float vp[4];
  #pragma unroll
  for (int k = 0; k < 4; ++k) vp[k] = NEGF;
  float vu_sh = NEGF, vd_sh = NEGF;

  auto fstage8 = [&](int rbase, int mlo) {
    #pragma unroll
    for (int q = 0; q < 8; ++q) {
      int m = mlo + q; m = m < 1 ? 1 : (m > 320 ? 320 : m);
      __builtin_amdgcn_global_load_lds((const void*)(thS + (size_t)m * 256 + 4 * t),
                                       (void*)&stg[rbase + q][0], 16, 0, 0);
      __builtin_amdgcn_global_load_lds((const void*)(aS + (size_t)m * 256 + 4 * t),
                                       (void*)&stg[rbase + 8 + q][0], 16, 0, 0);
    }
  };

  fstage8(0, 1); fstage8(16, 9); fstage8(32, 17);
  u32x4_t* qpt = qS + 64 + t;   // plane m=1
  for (int h = 0; h < 40; ++h) {
    const int m0 = 1 + 8 * h;
    const int R = (h % 3) * 16;
    if (h == 0)      WAITV(32);
    else if (h == 1) WAITV(40);
    else             WAITV(48);
    f32x4_t thc = stg[R][t], ac = stg[R + 8][t];
    f32x4_t thn, an;
    #pragma unroll
    for (int u = 0; u < 8; ++u) {
      if (u < 7) { thn = stg[R + u + 1][t]; an = stg[R + 8 + u + 1][t]; }
      SBAR();
      const int m = m0 + u;
      const int j = m - t;
      const bool actv = (j >= 1) && (j <= 256);
      float vu_in = vu_sh, vd_in = vd_sh;
      if (t == 0) { vu_in = NEGF; vd_in = (m == 1) ? 0.f : NEGF; }
      float x2v[4], m12[4];
      #pragma unroll
      for (int k = 0; k < 4; ++k) {
        x2v[k] = ac[k] + vp[k];
        const float vdk = (k == 0) ? vd_in : vp[k - 1];
        m12[k] = fmaxf(vdk, x2v[k]);
      }
      float vn[4], e0v[4], e2v[4], rzv[4];
      #pragma unroll
      for (int k = 0; k < 4; ++k) {
        const float vu  = (k == 0) ? vu_in : vn[k - 1];
        const float vdk = (k == 0) ? vd_in : vp[k - 1];
        const float x0 = ac[k] + vu;
        const float mx = fmaxf(x0, m12[k]);
        const float e0 = __builtin_amdgcn_exp2f(x0 - mx);
        const float e1 = __builtin_amdgcn_exp2f(vdk - mx);
        const float e2 = __builtin_amdgcn_exp2f(x2v[k] - mx);
        const float Z  = e0 + e1 + e2;
        rzv[k] = __builtin_amdgcn_rcpf(Z);
        const float v  = thc[k] + mx + __builtin_amdgcn_logf(Z);  // log2
        vn[k] = actv ? v : vp[k];
        e0v[k] = e0; e2v[k] = e2;
      }
      // shfl ASAP after chain end; packing/stores are off-chain and follow
      const float nsh = __shfl_up(vn[3], 1);
      uint32_t pk[4];
      #pragma unroll
      for (int k = 0; k < 4; ++k)
        pk[k] = pack_q(e0v[k] * rzv[k], e2v[k] * rzv[k]);  // (q1,q3)
      qpt[0] = u32x4_t{pk[0], pk[1], pk[2], pk[3]};
      qpt += 64;
      vd_sh = vu_sh; vu_sh = nsh;
      #pragma unroll
      for (int k = 0; k < 4; ++k) vp[k] = vn[k];
      if (u < 7) { thc = thn; ac = an; }
    }
    fstage8(R, m0 + 24);
  }

  DRAIN();  // qS RAW boundary (fwd stores -> bwd staged reads)

  // ================= backward =================
  float ep[4] = {0.f, 0.f, 0.f, 0.f};
  float sh_e1 = 0.f, sh_e2 = 0.f;
  uint32_t sh_q1 = 0u, sh_q2 = 0u;
  u32x4_t qm1 = u32x4_t{0u, 0u, 0u, 0u};
  const u32x4_t QONE = u32x4_t{0x3C00u, 0x3C00u, 0x3C00u, 0x3C00u};

  auto bstage = [&](int rbase, int Phi) {
    #pragma unroll
    for (int u = 0; u < 4; ++u) {
      int P = Phi - u; P = P < 0 ? 0 : (P > 320 ? 320 : P);
      __builtin_amdgcn_global_load_lds((const void*)(qS + (size_t)P * 64 + t),
                                       (void*)&stg[rbase + u][0], 16, 0, 0);
    }
  };

  bstage(0, 319); bstage(4, 315); bstage(8, 311);
  for (int n = 0; n < 80; ++n) {
    const int R = (n % 3) * 4;
    if (n == 0)      WAITV(8);
    else if (n == 1) WAITV(24);
    else             WAITV(40);
    u32x4_t cur = __builtin_bit_cast(u32x4_t, stg[R][t]);
    u32x4_t nxt;
    #pragma unroll
    for (int u = 0; u < 4; ++u) {
      if (u < 3) nxt = __builtin_bit_cast(u32x4_t, stg[R + u + 1][t]);
      SBAR();
      const int mp = 4 * n + u;
      const int P  = 319 - mp;
      const int j  = P - t;
      const bool actv = (j >= 1) && (j <= 256);
      const bool jok  = (j <= 255);
      const u32x4_t qmm = jok ? qm1 : QONE;
      const uint32_t sq1 = (t == 63) ? 0u : sh_q1;
      const uint32_t sq2 = (t == 63 || !jok) ? 0x3C00u : sh_q2;
      float en[4];
      #pragma unroll
      for (int kk = 0; kk < 4; ++kk) {
        const int k = 3 - kk;
        const uint32_t uA = (k < 3) ? cur[k + 1] : sq1;   // Q1 of (i+1, j)
        const uint32_t uB = (k < 3) ? qmm[k + 1] : sq2;   // Q of (i+1, j+1)
        const uint32_t uC = qmm[k];                       // Q3 of (i, j+1)
        const float2 fA = unpack_q(uA);
        const float2 fB = unpack_q(uB);
        const float2 fC = unpack_q(uC);
        const float q1u = fA.x;
        const float q2d = 1.f - fB.x - fB.y;
        const float q3l = fC.y;
        const float eu = (k < 3) ? en[k + 1] : sh_e1;
        const float ed = (k < 3) ? ep[k + 1] : sh_e2;
        const float el = ep[k];
        float E = q1u * eu + q2d * ed + q3l * el;
        if (n == 0 && u == 0 && k == 3) E = (t == 63) ? 1.f : E;  // seed
        en[k] = actv ? E : 0.f;
      }
      // shfls ASAP (en[0] is chain end), then direct ALN scatter (untwist
      // fused). Stores always issue: inactive lanes write the dump line.
      const float ne = __shfl_down(en[0], 1);
      const uint32_t nq = (uint32_t)__shfl_down((int)cur[0], 1);
      float* bp = actv ? (ALN + (size_t)(4 * t) * MM + (j - 1)) : dmp;
      const int st = actv ? MM : 0;
      bp[0] = en[0]; bp[st] = en[1]; bp[2 * st] = en[2]; bp[3 * st] = en[3];
      sh_e2 = sh_e1; sh_e1 = ne;
      sh_q2 = sh_q1; sh_q1 = nq;
      ep[0] = en[0]; ep[1] = en[1]; ep[2] = en[2]; ep[3] = en[3];
      qm1 = cur;
      if (u < 3) cur = nxt;
    }
    bstage(R, 307 - 4 * n);
  }
}

// ---------------- launcher ----------------
extern "C" void kernel_launch(void* const* d_in, const int* in_sizes, int n_in,
                              void* d_out, int out_size, void* d_ws, size_t ws_size,
                              hipStream_t stream) {
  const float* zx = (const float*)d_in[0];
  const float* zy = (const float*)d_in[1];
  const float* gx = (const float*)d_in[2];
  const float* gy = (const float*)d_in[3];

  float* out   = (float*)d_out;
  float* aln   = out;                              // [B][N][M]
  float* theta = out + (size_t)BB * NN * MM;       // [B][N][M]
  float* Amat  = out + (size_t)2 * BB * NN * MM;   // [B][N][M]

  float* ws  = (float*)d_ws;
  float* thS = ws;                                   // [B][321][256] f32
  float* aS  = ws + (size_t)BB * SPLN;               // [B][321][256] f32
  u32x4_t* qS = (u32x4_t*)(ws + (size_t)2 * BB * SPLN);  // [B][321][64] u32x4
  float* dmp = ws + (size_t)3 * BB * SPLN;           // [B][64] scribble

  gemm_mfma<<<dim3(4, 4, 64), 256, 0, stream>>>(zx, zy, gx, gy,
                                                theta, Amat, thS, aS);
  nw_wave<<<BB, 64, 0, stream>>>(thS, aS, qS, aln, dmp);
}